// Round 10
// baseline (756.250 us; speedup 1.0000x reference)
//
#include <hip/hip_runtime.h>

#define SEQ   8192
#define VOCAB 128000
#define L     64
#define NCH   128   // SEQ / L
#define VSL   256   // vocab rows per slice (LDS-staged)

// ws layout (float offsets)
#define OFF_CMB  0          // CmbT[k][t] : [20][8192] combined, k-major (640 KB)
#define OFF_CVEC 163840     // cvecT[k][m][i] : [64][128][10]
#define OFF_AMAX 245760     // amax[t] : 8192 x u64 packed (key<<32 | VOCAB-idx)
// total = 262,144 floats = 1.05 MB

// ---------------------------------------------------------------------------
// K1: gather embeddings -> CmbT rows 0..9; cvec_t = W_i2h[:,:10]*w_t + b_i2h;
//     zero the atomic-argmax array.
// ---------------------------------------------------------------------------
__global__ void k_embed(const int* __restrict__ ix, const float* __restrict__ emb,
                        const float* __restrict__ Wih, const float* __restrict__ bih,
                        float* __restrict__ ws) {
    int t = blockIdx.x * blockDim.x + threadIdx.x;
    if (t >= SEQ) return;

    ((unsigned long long*)(ws + OFF_AMAX))[t] = 0ULL;   // zero packed argmax

    int id = ix[t];
    float w[10];
    const float2* ep = (const float2*)(emb + (long long)id * 10);
#pragma unroll
    for (int j = 0; j < 5; j++) ((float2*)w)[j] = ep[j];

    // CmbT[j][t] = w[j]  (coalesced: consecutive t -> consecutive addr)
#pragma unroll
    for (int j = 0; j < 10; j++) ws[OFF_CMB + j * SEQ + t] = w[j];

    int m = t >> 6, k = t & 63;
    float* cv = ws + OFF_CVEC + (k * NCH + m) * 10;
#pragma unroll
    for (int i = 0; i < 10; i++) {
        float s = bih[i];
#pragma unroll
        for (int j = 0; j < 10; j++) s += Wih[i * 20 + j] * w[j];
        cv[i] = s;
    }
}

// ---------------------------------------------------------------------------
// K3: blocked scan of h_{t+1} = A h_t + c_t; writes h_t into CmbT rows 10..19
// Phases A/C: c loaded as 5x float2 (40B rows are 8B-aligned) with one-step
// software prefetch -> latency off the critical path (was 10 scalar loads).
// ---------------------------------------------------------------------------
__global__ void k_scan(const float* __restrict__ Wih, float* __restrict__ ws) {
    __shared__ float P[100], Q[100];
    __shared__ float Dl[NCH][10];
    __shared__ float Hst[NCH][10];
    __shared__ float Hl[10];
    int tid = threadIdx.x;

    float Ar[10][10];
#pragma unroll
    for (int i = 0; i < 10; i++)
#pragma unroll
        for (int j = 0; j < 10; j++) Ar[i][j] = Wih[i * 20 + 10 + j];

    // ---- phase A: each thread = one chunk, from zero state ----
    {
        int m = tid;
        float h[10];
#pragma unroll
        for (int i = 0; i < 10; i++) h[i] = 0.f;
        const float* cvb = ws + OFF_CVEC;
        float2 buf[5];
        {
            const float2* cp = (const float2*)(cvb + (0 * NCH + m) * 10);
#pragma unroll
            for (int j = 0; j < 5; j++) buf[j] = cp[j];
        }
        for (int k = 0; k < L; k++) {
            float cc[10];
#pragma unroll
            for (int j = 0; j < 5; j++) { cc[2 * j] = buf[j].x; cc[2 * j + 1] = buf[j].y; }
            if (k + 1 < L) {
                const float2* cp = (const float2*)(cvb + ((k + 1) * NCH + m) * 10);
#pragma unroll
                for (int j = 0; j < 5; j++) buf[j] = cp[j];
            }
            float nh[10];
#pragma unroll
            for (int i = 0; i < 10; i++) {
                float s = cc[i];
#pragma unroll
                for (int j = 0; j < 10; j++) s += Ar[i][j] * h[j];
                nh[i] = s;
            }
#pragma unroll
            for (int i = 0; i < 10; i++) h[i] = nh[i];
        }
#pragma unroll
        for (int i = 0; i < 10; i++) Dl[m][i] = h[i];
    }

    // ---- phase B1: A^64 via 6 squarings ----
    if (tid < 100) P[tid] = Wih[(tid / 10) * 20 + 10 + (tid % 10)];
    __syncthreads();
    for (int it = 0; it < 6; it++) {
        if (tid < 100) {
            int i = tid / 10, j = tid % 10;
            float s = 0.f;
#pragma unroll
            for (int k = 0; k < 10; k++) s += P[i * 10 + k] * P[k * 10 + j];
            Q[tid] = s;
        }
        __syncthreads();
        if (tid < 100) P[tid] = Q[tid];
        __syncthreads();
    }

    // ---- phase B2: chunk-boundary scan (lanes 0..9, wave-lockstep) ----
    if (tid < 10) Hl[tid] = 0.f;
    __syncthreads();
    if (tid < 10) {
        int i = tid;
        float a64[10];
#pragma unroll
        for (int j = 0; j < 10; j++) a64[j] = P[i * 10 + j];
        float hc = 0.f;
        for (int m = 0; m < NCH; m++) {
            Hst[m][i] = hc;
            float s = Dl[m][i];
#pragma unroll
            for (int j = 0; j < 10; j++) s += a64[j] * Hl[j];
            Hl[i] = s;
            hc = s;
        }
    }
    __syncthreads();

    // ---- phase C: re-run with true starts; CmbT[10+i][m*64+k] = h_t ----
    {
        int m = tid;
        float h[10];
#pragma unroll
        for (int i = 0; i < 10; i++) h[i] = Hst[m][i];
        const float* cvb = ws + OFF_CVEC;
        float2 buf[5];
        {
            const float2* cp = (const float2*)(cvb + (0 * NCH + m) * 10);
#pragma unroll
            for (int j = 0; j < 5; j++) buf[j] = cp[j];
        }
        for (int k = 0; k < L; k++) {
            int tg = m * 64 + k;
            float cc[10];
#pragma unroll
            for (int j = 0; j < 5; j++) { cc[2 * j] = buf[j].x; cc[2 * j + 1] = buf[j].y; }
            if (k + 1 < L) {
                const float2* cp = (const float2*)(cvb + ((k + 1) * NCH + m) * 10);
#pragma unroll
                for (int j = 0; j < 5; j++) buf[j] = cp[j];
            }
#pragma unroll
            for (int i = 0; i < 10; i++) ws[OFF_CMB + (10 + i) * SEQ + tg] = h[i];
            float nh[10];
#pragma unroll
            for (int i = 0; i < 10; i++) {
                float s = cc[i];
#pragma unroll
                for (int j = 0; j < 10; j++) s += Ar[i][j] * h[j];
                nh[i] = s;
            }
#pragma unroll
            for (int i = 0; i < 10; i++) h[i] = nh[i];
        }
    }
}

// ---------------------------------------------------------------------------
// K4: fused logits + argmax, 4 timesteps per thread, W slice in LDS.
// Grid: 4000 = 500 v-slices (256 v) x 8 t-tiles (1024 t). Block: 256 thr.
// Thread owns t0 + {0,256,512,768} with c[4][20] in VGPRs. Per row-pair:
// 10x ds_read_b128 (2 rows, contiguous) + 1 ds_read_b64 (bias) feed 160 FMAs.
// Single 20-FMA chain per (row,q), SEEDED BY BIAS via v_fma (no movs/final
// add); 8 independent chains cover dep latency. waves_per_eu(1,2): register
// budget >=256 so the ~140-reg live set stays in arch VGPRs (R7/8/9 got
// 36/60/84 VGPRs -> AGPR shuttling, ~1.4x VALU issue bloat).
// Argmax purely per-lane (ascending v, strict >); 4 packed-u64 atomicMax.
// ---------------------------------------------------------------------------
__global__ __launch_bounds__(256)
__attribute__((amdgpu_waves_per_eu(1, 2)))
void k_logits(const float* __restrict__ ws, const float* __restrict__ Wio,
              const float* __restrict__ bio, unsigned long long* __restrict__ amax) {
    __shared__ float Wl[VSL * 20];   // 20 KB, row-major [v][20]
    __shared__ float Bl[VSL];        // 1 KB

    int tid = threadIdx.x;
    int sl  = blockIdx.x % 500;      // v-slice
    int tt  = blockIdx.x / 500;      // t-tile
    int v0  = sl * VSL;

    // ---- stage W slice: 1280 float4, 5 per thread (contiguous, coalesced) ----
    {
        const float4* Wg = (const float4*)(Wio + (long long)v0 * 20);
        float4* Wl4 = (float4*)Wl;
#pragma unroll
        for (int r = 0; r < 5; r++) Wl4[tid + 256 * r] = Wg[tid + 256 * r];
        if (tid < 64) ((float4*)Bl)[tid] = ((const float4*)(bio + v0))[tid];
    }
    __syncthreads();

    int t0 = tt * 1024 + tid;        // this thread's t's: t0 + {0,256,512,768}

    // per-thread combined vectors (coalesced: consecutive tid -> consecutive t)
    float c[4][20];
    const float* cmb = ws + OFF_CMB;
#pragma unroll
    for (int k = 0; k < 20; k++) {
#pragma unroll
        for (int q = 0; q < 4; q++) c[q][k] = cmb[k * SEQ + t0 + q * 256];
    }

    float best[4];
    int   bidx[4];
#pragma unroll
    for (int q = 0; q < 4; q++) { best[q] = -3.4e38f; bidx[q] = 0; }

    for (int r = 0; r < VSL; r += 2) {
        // 2 rows = 40 contiguous floats = 10 float4 (rows are 80 B, r even -> 16B-aligned)
        float4 wr[10];
        {
            const float4* rp = (const float4*)(Wl + r * 20);
#pragma unroll
            for (int q = 0; q < 10; q++) wr[q] = rp[q];
        }
        float2 bb = *(const float2*)(Bl + r);
        const float* w = (const float*)wr;

#pragma unroll
        for (int rr = 0; rr < 2; rr++) {
            float bias = rr ? bb.y : bb.x;
            int   v    = v0 + r + rr;
#pragma unroll
            for (int q = 0; q < 4; q++) {
                float a = fmaf(w[rr * 20], c[q][0], bias);
#pragma unroll
                for (int k = 1; k < 20; k++) a = fmaf(w[rr * 20 + k], c[q][k], a);
                if (a > best[q]) { best[q] = a; bidx[q] = v; }
            }
        }
    }

    // per-lane global merge (exact jnp.argmax semantics: max value, lowest idx)
#pragma unroll
    for (int q = 0; q < 4; q++) {
        unsigned int u = __float_as_uint(best[q]);
        unsigned int key = (u & 0x80000000u) ? ~u : (u | 0x80000000u);
        unsigned long long packed =
            ((unsigned long long)key << 32) | (unsigned int)(VOCAB - bidx[q]);
        atomicMax(&amax[t0 + q * 256], packed);
    }
}

// ---------------------------------------------------------------------------
// K5: unpack argmax -> float index
// ---------------------------------------------------------------------------
__global__ void k_out(const unsigned long long* __restrict__ amax,
                      float* __restrict__ out) {
    int t = blockIdx.x * blockDim.x + threadIdx.x;
    if (t >= SEQ) return;
    unsigned long long p = amax[t];
    int idx = VOCAB - (int)(p & 0xFFFFFFFFu);
    out[t] = (float)idx;
}

// ---------------------------------------------------------------------------
extern "C" void kernel_launch(void* const* d_in, const int* in_sizes, int n_in,
                              void* d_out, int out_size, void* d_ws, size_t ws_size,
                              hipStream_t stream) {
    (void)in_sizes; (void)n_in; (void)out_size; (void)ws_size;
    const int*   ix  = (const int*)d_in[0];
    const float* emb = (const float*)d_in[1];
    const float* Wih = (const float*)d_in[2];
    const float* bih = (const float*)d_in[3];
    const float* Wio = (const float*)d_in[4];
    const float* bio = (const float*)d_in[5];
    float* out = (float*)d_out;
    float* ws  = (float*)d_ws;
    unsigned long long* amax = (unsigned long long*)(ws + OFF_AMAX);

    hipLaunchKernelGGL(k_embed,  dim3(SEQ / 256), dim3(256), 0, stream, ix, emb, Wih, bih, ws);
    hipLaunchKernelGGL(k_scan,   dim3(1), dim3(128), 0, stream, Wih, ws);
    hipLaunchKernelGGL(k_logits, dim3(4000), dim3(256), 0, stream, ws, Wio, bio, amax);
    hipLaunchKernelGGL(k_out,    dim3(SEQ / 256), dim3(256), 0, stream, amax, out);
}

// Round 11
// 640.426 us; speedup vs baseline: 1.1809x; 1.1809x over previous
//
#include <hip/hip_runtime.h>

#define SEQ   8192
#define VOCAB 128000
#define L     64
#define NCH   128   // SEQ / L
#define VSL   256   // vocab rows per slice (LDS-staged)

// ws layout (float offsets)
#define OFF_CMB  0          // CmbT[k][t] : [20][8192] combined, k-major (640 KB)
#define OFF_CVEC 163840     // cvecT[k][m][i] : [64][128][10]
#define OFF_AMAX 245760     // amax[t] : 8192 x u64 packed (key<<32 | VOCAB-idx)
// total = 262,144 floats = 1.05 MB

// ---------------------------------------------------------------------------
// K1: gather embeddings -> CmbT rows 0..9; cvec_t = W_i2h[:,:10]*w_t + b_i2h;
//     zero the atomic-argmax array.
// ---------------------------------------------------------------------------
__global__ void k_embed(const int* __restrict__ ix, const float* __restrict__ emb,
                        const float* __restrict__ Wih, const float* __restrict__ bih,
                        float* __restrict__ ws) {
    int t = blockIdx.x * blockDim.x + threadIdx.x;
    if (t >= SEQ) return;

    ((unsigned long long*)(ws + OFF_AMAX))[t] = 0ULL;   // zero packed argmax

    int id = ix[t];
    float w[10];
    const float2* ep = (const float2*)(emb + (long long)id * 10);
#pragma unroll
    for (int j = 0; j < 5; j++) ((float2*)w)[j] = ep[j];

    // CmbT[j][t] = w[j]  (coalesced: consecutive t -> consecutive addr)
#pragma unroll
    for (int j = 0; j < 10; j++) ws[OFF_CMB + j * SEQ + t] = w[j];

    int m = t >> 6, k = t & 63;
    float* cv = ws + OFF_CVEC + (k * NCH + m) * 10;
#pragma unroll
    for (int i = 0; i < 10; i++) {
        float s = bih[i];
#pragma unroll
        for (int j = 0; j < 10; j++) s += Wih[i * 20 + j] * w[j];
        cv[i] = s;
    }
}

// ---------------------------------------------------------------------------
// K3: blocked scan of h_{t+1} = A h_t + c_t; writes h_t into CmbT rows 10..19
// Phases A/C: c loaded as 5x float2 with one-step software prefetch.
// ---------------------------------------------------------------------------
__global__ void k_scan(const float* __restrict__ Wih, float* __restrict__ ws) {
    __shared__ float P[100], Q[100];
    __shared__ float Dl[NCH][10];
    __shared__ float Hst[NCH][10];
    __shared__ float Hl[10];
    int tid = threadIdx.x;

    float Ar[10][10];
#pragma unroll
    for (int i = 0; i < 10; i++)
#pragma unroll
        for (int j = 0; j < 10; j++) Ar[i][j] = Wih[i * 20 + 10 + j];

    // ---- phase A: each thread = one chunk, from zero state ----
    {
        int m = tid;
        float h[10];
#pragma unroll
        for (int i = 0; i < 10; i++) h[i] = 0.f;
        const float* cvb = ws + OFF_CVEC;
        float2 buf[5];
        {
            const float2* cp = (const float2*)(cvb + (0 * NCH + m) * 10);
#pragma unroll
            for (int j = 0; j < 5; j++) buf[j] = cp[j];
        }
        for (int k = 0; k < L; k++) {
            float cc[10];
#pragma unroll
            for (int j = 0; j < 5; j++) { cc[2 * j] = buf[j].x; cc[2 * j + 1] = buf[j].y; }
            if (k + 1 < L) {
                const float2* cp = (const float2*)(cvb + ((k + 1) * NCH + m) * 10);
#pragma unroll
                for (int j = 0; j < 5; j++) buf[j] = cp[j];
            }
            float nh[10];
#pragma unroll
            for (int i = 0; i < 10; i++) {
                float s = cc[i];
#pragma unroll
                for (int j = 0; j < 10; j++) s += Ar[i][j] * h[j];
                nh[i] = s;
            }
#pragma unroll
            for (int i = 0; i < 10; i++) h[i] = nh[i];
        }
#pragma unroll
        for (int i = 0; i < 10; i++) Dl[m][i] = h[i];
    }

    // ---- phase B1: A^64 via 6 squarings ----
    if (tid < 100) P[tid] = Wih[(tid / 10) * 20 + 10 + (tid % 10)];
    __syncthreads();
    for (int it = 0; it < 6; it++) {
        if (tid < 100) {
            int i = tid / 10, j = tid % 10;
            float s = 0.f;
#pragma unroll
            for (int k = 0; k < 10; k++) s += P[i * 10 + k] * P[k * 10 + j];
            Q[tid] = s;
        }
        __syncthreads();
        if (tid < 100) P[tid] = Q[tid];
        __syncthreads();
    }

    // ---- phase B2: chunk-boundary scan (lanes 0..9, wave-lockstep) ----
    if (tid < 10) Hl[tid] = 0.f;
    __syncthreads();
    if (tid < 10) {
        int i = tid;
        float a64[10];
#pragma unroll
        for (int j = 0; j < 10; j++) a64[j] = P[i * 10 + j];
        float hc = 0.f;
        for (int m = 0; m < NCH; m++) {
            Hst[m][i] = hc;
            float s = Dl[m][i];
#pragma unroll
            for (int j = 0; j < 10; j++) s += a64[j] * Hl[j];
            Hl[i] = s;
            hc = s;
        }
    }
    __syncthreads();

    // ---- phase C: re-run with true starts; CmbT[10+i][m*64+k] = h_t ----
    {
        int m = tid;
        float h[10];
#pragma unroll
        for (int i = 0; i < 10; i++) h[i] = Hst[m][i];
        const float* cvb = ws + OFF_CVEC;
        float2 buf[5];
        {
            const float2* cp = (const float2*)(cvb + (0 * NCH + m) * 10);
#pragma unroll
            for (int j = 0; j < 5; j++) buf[j] = cp[j];
        }
        for (int k = 0; k < L; k++) {
            int tg = m * 64 + k;
            float cc[10];
#pragma unroll
            for (int j = 0; j < 5; j++) { cc[2 * j] = buf[j].x; cc[2 * j + 1] = buf[j].y; }
            if (k + 1 < L) {
                const float2* cp = (const float2*)(cvb + ((k + 1) * NCH + m) * 10);
#pragma unroll
                for (int j = 0; j < 5; j++) buf[j] = cp[j];
            }
#pragma unroll
            for (int i = 0; i < 10; i++) ws[OFF_CMB + (10 + i) * SEQ + tg] = h[i];
            float nh[10];
#pragma unroll
            for (int i = 0; i < 10; i++) {
                float s = cc[i];
#pragma unroll
                for (int j = 0; j < 10; j++) s += Ar[i][j] * h[j];
                nh[i] = s;
            }
#pragma unroll
            for (int i = 0; i < 10; i++) h[i] = nh[i];
        }
    }
}

// ---------------------------------------------------------------------------
// K4: fused logits + argmax, 4 timesteps per thread, W slice in LDS.
// R9 body (best-known: dual 10-FMA chains, 160 FMA per 11 DS) with ONE
// change: __launch_bounds__(256, 2). Evidence (R3/R5 vs R7-R10): the
// launch_bounds 2nd arg, not amdgpu_waves_per_eu, controls the VGPR grant:
// (256,2) granted 128 both times; waves_per_eu variants granted 36-88,
// forcing ~50 live values into AGPRs with v_accvgpr_read shuttling (~1.5x
// VALU issue bloat: modeled 316 us busy vs 488 observed in R9). At 128
// regs: live ~136 -> ~8 shuttled only, and HW occupancy rises to 4 waves/EU
// (LDS 21.5 KB allows 7 blocks/CU), covering the per-row-pair LDS stall.
// Argmax purely per-lane (ascending v, strict >); 4 packed-u64 atomicMax.
// ---------------------------------------------------------------------------
__global__ __launch_bounds__(256, 2)
void k_logits(const float* __restrict__ ws, const float* __restrict__ Wio,
              const float* __restrict__ bio, unsigned long long* __restrict__ amax) {
    __shared__ float Wl[VSL * 20];   // 20 KB, row-major [v][20]
    __shared__ float Bl[VSL];        // 1 KB

    int tid = threadIdx.x;
    int sl  = blockIdx.x % 500;      // v-slice
    int tt  = blockIdx.x / 500;      // t-tile
    int v0  = sl * VSL;

    // ---- stage W slice: 1280 float4, 5 per thread (contiguous, coalesced) ----
    {
        const float4* Wg = (const float4*)(Wio + (long long)v0 * 20);
        float4* Wl4 = (float4*)Wl;
#pragma unroll
        for (int r = 0; r < 5; r++) Wl4[tid + 256 * r] = Wg[tid + 256 * r];
        if (tid < 64) ((float4*)Bl)[tid] = ((const float4*)(bio + v0))[tid];
    }
    __syncthreads();

    int t0 = tt * 1024 + tid;        // this thread's t's: t0 + {0,256,512,768}

    // per-thread combined vectors (coalesced: consecutive tid -> consecutive t)
    float c[4][20];
    const float* cmb = ws + OFF_CMB;
#pragma unroll
    for (int k = 0; k < 20; k++) {
#pragma unroll
        for (int q = 0; q < 4; q++) c[q][k] = cmb[k * SEQ + t0 + q * 256];
    }

    float best[4];
    int   bidx[4];
#pragma unroll
    for (int q = 0; q < 4; q++) { best[q] = -3.4e38f; bidx[q] = 0; }

    for (int r = 0; r < VSL; r += 2) {
        float4 w0[5], w1[5];
        {
            const float4* rp0 = (const float4*)(Wl + r * 20);
            const float4* rp1 = (const float4*)(Wl + (r + 1) * 20);
#pragma unroll
            for (int q = 0; q < 5; q++) { w0[q] = rp0[q]; w1[q] = rp1[q]; }
        }
        float2 bb = *(const float2*)(Bl + r);

        // row r
        {
            const float* w = (const float*)w0;
#pragma unroll
            for (int q = 0; q < 4; q++) {
                float a0 = bb.x, a1 = 0.f;
#pragma unroll
                for (int k = 0; k < 10; k++) {
                    a0 += w[k]      * c[q][k];
                    a1 += w[10 + k] * c[q][10 + k];
                }
                float l = a0 + a1;
                if (l > best[q]) { best[q] = l; bidx[q] = v0 + r; }
            }
        }
        // row r+1
        {
            const float* w = (const float*)w1;
#pragma unroll
            for (int q = 0; q < 4; q++) {
                float a0 = bb.y, a1 = 0.f;
#pragma unroll
                for (int k = 0; k < 10; k++) {
                    a0 += w[k]      * c[q][k];
                    a1 += w[10 + k] * c[q][10 + k];
                }
                float l = a0 + a1;
                if (l > best[q]) { best[q] = l; bidx[q] = v0 + r + 1; }
            }
        }
    }

    // per-lane global merge (exact jnp.argmax semantics: max value, lowest idx)
#pragma unroll
    for (int q = 0; q < 4; q++) {
        unsigned int u = __float_as_uint(best[q]);
        unsigned int key = (u & 0x80000000u) ? ~u : (u | 0x80000000u);
        unsigned long long packed =
            ((unsigned long long)key << 32) | (unsigned int)(VOCAB - bidx[q]);
        atomicMax(&amax[t0 + q * 256], packed);
    }
}

// ---------------------------------------------------------------------------
// K5: unpack argmax -> float index
// ---------------------------------------------------------------------------
__global__ void k_out(const unsigned long long* __restrict__ amax,
                      float* __restrict__ out) {
    int t = blockIdx.x * blockDim.x + threadIdx.x;
    if (t >= SEQ) return;
    unsigned long long p = amax[t];
    int idx = VOCAB - (int)(p & 0xFFFFFFFFu);
    out[t] = (float)idx;
}

// ---------------------------------------------------------------------------
extern "C" void kernel_launch(void* const* d_in, const int* in_sizes, int n_in,
                              void* d_out, int out_size, void* d_ws, size_t ws_size,
                              hipStream_t stream) {
    (void)in_sizes; (void)n_in; (void)out_size; (void)ws_size;
    const int*   ix  = (const int*)d_in[0];
    const float* emb = (const float*)d_in[1];
    const float* Wih = (const float*)d_in[2];
    const float* bih = (const float*)d_in[3];
    const float* Wio = (const float*)d_in[4];
    const float* bio = (const float*)d_in[5];
    float* out = (float*)d_out;
    float* ws  = (float*)d_ws;
    unsigned long long* amax = (unsigned long long*)(ws + OFF_AMAX);

    hipLaunchKernelGGL(k_embed,  dim3(SEQ / 256), dim3(256), 0, stream, ix, emb, Wih, bih, ws);
    hipLaunchKernelGGL(k_scan,   dim3(1), dim3(128), 0, stream, Wih, ws);
    hipLaunchKernelGGL(k_logits, dim3(4000), dim3(256), 0, stream, ws, Wio, bio, amax);
    hipLaunchKernelGGL(k_out,    dim3(SEQ / 256), dim3(256), 0, stream, amax, out);
}